// Round 3
// baseline (166.671 us; speedup 1.0000x reference)
//
#include <hip/hip_runtime.h>
#include <hip/hip_bf16.h>

// TypedLinear: y[i] = W[types[i]] @ x[i] + b[types[i]]
// B=131072 tokens, T=8 types, IN=OUT=128, all fp32 in/out.
// Strategy: per-block type bucketing + bf16 MFMA (16x16x32), memory-bound target ~21us.

typedef __attribute__((ext_vector_type(8))) short bf16x8;   // 8 bf16 in 4 VGPRs (guide-blessed operand type)
typedef __attribute__((ext_vector_type(4))) float f32x4;    // MFMA accumulator
typedef __attribute__((ext_vector_type(4))) float float4v;

static constexpr int kBT = 128;   // tokens per block
static constexpr int kT  = 8;     // number of types
static constexpr int kD  = 128;   // IN = OUT = 128

__device__ __forceinline__ short f2bf(float f) {
  // RNE float->bf16 via HIP intrinsic (compiler fuses to packed cvt)
  union { __hip_bfloat16 h; short u; } cv;
  cv.h = __float2bfloat16(f);
  return cv.u;
}

// Prep: convert W (8*128*128 fp32) -> bf16 in workspace (256 KiB, L2-resident).
__global__ __launch_bounds__(256) void wconv_kernel(const float* __restrict__ W,
                                                    short* __restrict__ Wb) {
  const int i = (blockIdx.x * 256 + threadIdx.x) * 8;
  float4v a = *(const float4v*)(W + i);
  float4v b = *(const float4v*)(W + i + 4);
  bf16x8 r;
  r[0] = f2bf(a[0]); r[1] = f2bf(a[1]); r[2] = f2bf(a[2]); r[3] = f2bf(a[3]);
  r[4] = f2bf(b[0]); r[5] = f2bf(b[1]); r[6] = f2bf(b[2]); r[7] = f2bf(b[3]);
  *(bf16x8*)(Wb + i) = r;
}

// Main kernel: 256 threads = 4 waves. Block handles kBT=128 consecutive tokens.
// Wave w owns output columns [w*32, w*32+32) (2 column-tiles of 16).
// Per type t: W[t] fragments live in 32 VGPRs/wave; token rows gathered per 16-row
// MFMA tile via the LDS bucket list.
__global__ __launch_bounds__(256, 4) void typed_linear_kernel(
    const float* __restrict__ x, const int* __restrict__ types,
    const short* __restrict__ Wb, const float* __restrict__ bias,
    float* __restrict__ y) {
  __shared__ int s_cnt[kT];
  __shared__ unsigned char s_list[kT][kBT];

  const int tid = threadIdx.x;
  if (tid < kT) s_cnt[tid] = 0;
  __syncthreads();
  const int tok0 = blockIdx.x * kBT;
  if (tid < kBT) {
    const int t = types[tok0 + tid];
    const int pos = atomicAdd(&s_cnt[t], 1);
    s_list[t][pos] = (unsigned char)tid;
  }
  __syncthreads();

  const int w    = tid >> 6;    // wave id 0..3
  const int lane = tid & 63;
  const int lr   = lane & 15;   // A-row / B-col / C-col key
  const int lg   = lane >> 4;   // k-group 0..3

  for (int t = 0; t < kT; ++t) {
    const int cnt = s_cnt[t];               // uniform across block
    if (cnt == 0) continue;

    // B fragments: B[k][o] = W[t][o][k]; lane reads 8 contiguous bf16 along k.
    // (A and B use the SAME assumed k-map => result correct for any HW k-bijection.)
    bf16x8 bfr[2][4];
    const short* wrow = Wb + ((t * kD + w * 32 + lr) * kD);
#pragma unroll
    for (int c = 0; c < 2; ++c)
#pragma unroll
      for (int s = 0; s < 4; ++s)
        bfr[c][s] = *(const bf16x8*)(wrow + c * 16 * kD + s * 32 + lg * 8);

    const float bias0 = bias[t * kD + w * 32 + lr];
    const float bias1 = bias[t * kD + w * 32 + 16 + lr];

    for (int m0 = 0; m0 < cnt; m0 += 16) {
      // A fragment: row = lr (clamped duplicate for ragged tail; masked at store)
      int ia = m0 + lr;
      ia = ia < cnt ? ia : cnt - 1;
      const float* xr = x + (size_t)(tok0 + s_list[t][ia]) * kD;
      bf16x8 afr[4];
#pragma unroll
      for (int s = 0; s < 4; ++s) {
        float4v u0 = *(const float4v*)(xr + s * 32 + lg * 8);
        float4v u1 = *(const float4v*)(xr + s * 32 + lg * 8 + 4);
        bf16x8 a;
        a[0] = f2bf(u0[0]); a[1] = f2bf(u0[1]); a[2] = f2bf(u0[2]); a[3] = f2bf(u0[3]);
        a[4] = f2bf(u1[0]); a[5] = f2bf(u1[1]); a[6] = f2bf(u1[2]); a[7] = f2bf(u1[3]);
        afr[s] = a;
      }

      f32x4 acc0 = {0.f, 0.f, 0.f, 0.f};
      f32x4 acc1 = {0.f, 0.f, 0.f, 0.f};
#pragma unroll
      for (int s = 0; s < 4; ++s) {
        acc0 = __builtin_amdgcn_mfma_f32_16x16x32_bf16(afr[s], bfr[0][s], acc0, 0, 0, 0);
        acc1 = __builtin_amdgcn_mfma_f32_16x16x32_bf16(afr[s], bfr[1][s], acc1, 0, 0, 0);
      }

      // C/D layout (HW-verified): col = lane&15, row = (lane>>4)*4 + reg
#pragma unroll
      for (int r = 0; r < 4; ++r) {
        const int rl = lg * 4 + r;
        if (m0 + rl < cnt) {
          float* yp = y + (size_t)(tok0 + s_list[t][m0 + rl]) * kD + w * 32 + lr;
          yp[0]  = acc0[r] + bias0;
          yp[16] = acc1[r] + bias1;
        }
      }
    }
  }
}

extern "C" void kernel_launch(void* const* d_in, const int* in_sizes, int n_in,
                              void* d_out, int out_size, void* d_ws, size_t ws_size,
                              hipStream_t stream) {
  const float* x     = (const float*)d_in[0];
  const int*   types = (const int*)d_in[1];
  const float* W     = (const float*)d_in[2];
  const float* bias  = (const float*)d_in[3];
  float*       y     = (float*)d_out;
  short*       Wb    = (short*)d_ws;   // 8*128*128 bf16 = 256 KiB scratch

  const int n_tok = in_sizes[0] / kD;  // 131072

  wconv_kernel<<<(kT * kD * kD) / (256 * 8), 256, 0, stream>>>(W, Wb);
  typed_linear_kernel<<<n_tok / kBT, 256, 0, stream>>>(x, types, Wb, bias, y);
}

// Round 5
// 142.265 us; speedup vs baseline: 1.1716x; 1.1716x over previous
//
#include <hip/hip_runtime.h>
#include <hip/hip_bf16.h>

// TypedLinear: y[i] = W[types[i]] @ x[i] + b[types[i]]
// B=131072, T=8, IN=OUT=128, fp32 in/out.
// v2: bulk-coalesced reg-staging of x into a swizzled bf16 LDS tile (fixes the
// latency-bound gather of v1: 78us @ 1.28 TB/s, occupancy 30%, nothing saturated).
// Bucketed per-type MFMA compute unchanged (verified: absmax 0.031).

typedef __attribute__((ext_vector_type(8))) short bf16x8;   // 8 bf16 (one ds_read_b128)
typedef __attribute__((ext_vector_type(4))) short short4v;  // 4 bf16 (one ds_write_b64)
typedef __attribute__((ext_vector_type(4))) float f32x4;    // MFMA accumulator
typedef __attribute__((ext_vector_type(4))) float float4v;

static constexpr int kBT = 128;   // tokens per block
static constexpr int kT  = 8;     // number of types
static constexpr int kD  = 128;   // IN = OUT = 128

__device__ __forceinline__ short f2bf(float f) {
  union { __hip_bfloat16 h; short u; } cv;
  cv.h = __float2bfloat16(f);
  return cv.u;
}

// Prep: convert W (8*128*128 fp32) -> bf16 in workspace (256 KiB, L2-resident).
__global__ __launch_bounds__(256) void wconv_kernel(const float* __restrict__ W,
                                                    short* __restrict__ Wb) {
  const int i = (blockIdx.x * 256 + threadIdx.x) * 8;
  float4v a = *(const float4v*)(W + i);
  float4v b = *(const float4v*)(W + i + 4);
  bf16x8 r;
  r[0] = f2bf(a[0]); r[1] = f2bf(a[1]); r[2] = f2bf(a[2]); r[3] = f2bf(a[3]);
  r[4] = f2bf(b[0]); r[5] = f2bf(b[1]); r[6] = f2bf(b[2]); r[7] = f2bf(b[3]);
  *(bf16x8*)(Wb + i) = r;
}

// 256 threads = 4 waves; block = 128 consecutive tokens.
// Phase A: stage x-slice (64KB fp32) via 16 coalesced float4 loads/thread ->
//          cvt bf16 -> swizzled LDS tile xb[128][128] (32KB; 16B slot ^= row&7).
// Phase B: bucket tokens by type via LDS atomics.
// Phase C: per type: W frags (2 coltiles x 4 ksteps, 32 VGPR) from L2-resident Wb;
//          A frags gathered from LDS (cheap); 8x mfma_16x16x32_bf16; masked stores.
__global__ __launch_bounds__(256, 4) void typed_linear_kernel(
    const float* __restrict__ x, const int* __restrict__ types,
    const short* __restrict__ Wb, const float* __restrict__ bias,
    float* __restrict__ y) {
  __shared__ short xb[kBT * kD];            // 32 KiB swizzled bf16 x-tile
  __shared__ int s_cnt[kT];
  __shared__ unsigned char s_list[kT][kBT];

  const int tid  = threadIdx.x;
  const int tok0 = blockIdx.x * kBT;

  // --- Phase A1: issue all 16 coalesced global loads up-front (256B/thread in flight)
  const float* xg = x + (size_t)tok0 * kD;
  float4v xr[16];
#pragma unroll
  for (int i = 0; i < 16; ++i)
    xr[i] = *(const float4v*)(xg + i * 1024 + tid * 4);

  // --- Phase B: bucket by type (overlaps with x-load latency)
  if (tid < kT) s_cnt[tid] = 0;
  __syncthreads();
  if (tid < kBT) {
    const int t = types[tok0 + tid];
    const int pos = atomicAdd(&s_cnt[t], 1);
    s_list[t][pos] = (unsigned char)tid;
  }

  // --- Phase A2: cvt + swizzled LDS writes (slot ^= row&7 on 16B granules)
#pragma unroll
  for (int i = 0; i < 16; ++i) {
    const int f    = i * 1024 + tid * 4;    // flat float index in 128x128 slice
    const int row  = f >> 7;
    const int col  = f & 127;               // col%8 in {0,4}
    const int slot = (col >> 3) ^ (row & 7);
    short4v v;
    v[0] = f2bf(xr[i][0]); v[1] = f2bf(xr[i][1]);
    v[2] = f2bf(xr[i][2]); v[3] = f2bf(xr[i][3]);
    *(short4v*)(xb + row * kD + slot * 8 + (col & 7)) = v;
  }
  __syncthreads();

  const int w    = tid >> 6;    // wave id 0..3 -> owns output cols [w*32, w*32+32)
  const int lane = tid & 63;
  const int lr   = lane & 15;   // A-row / B-col / C-col key
  const int lg   = lane >> 4;   // k-group 0..3

  for (int t = 0; t < kT; ++t) {
    const int cnt = s_cnt[t];
    if (cnt == 0) continue;

    // B fragments: B[k][o] = W[t][o][k]; same assumed k-map as A (any shared
    // bijection over k is correct).
    bf16x8 bfr[2][4];
    const short* wrow = Wb + ((t * kD + w * 32 + lr) * kD);
#pragma unroll
    for (int c = 0; c < 2; ++c)
#pragma unroll
      for (int s = 0; s < 4; ++s)
        bfr[c][s] = *(const bf16x8*)(wrow + c * 16 * kD + s * 32 + lg * 8);

    const float bias0 = bias[t * kD + w * 32 + lr];
    const float bias1 = bias[t * kD + w * 32 + 16 + lr];

    for (int m0 = 0; m0 < cnt; m0 += 16) {
      int ia = m0 + lr;
      ia = ia < cnt ? ia : cnt - 1;         // clamped dup for ragged tail
      const int row = s_list[t][ia];

      // A fragments from swizzled LDS: slot = (s*4+lg) ^ (row&7)
      bf16x8 afr[4];
#pragma unroll
      for (int s = 0; s < 4; ++s) {
        const int slot = ((s << 2) + lg) ^ (row & 7);
        afr[s] = *(const bf16x8*)(xb + row * kD + slot * 8);
      }

      f32x4 acc0 = {0.f, 0.f, 0.f, 0.f};
      f32x4 acc1 = {0.f, 0.f, 0.f, 0.f};
#pragma unroll
      for (int s = 0; s < 4; ++s) {
        acc0 = __builtin_amdgcn_mfma_f32_16x16x32_bf16(afr[s], bfr[0][s], acc0, 0, 0, 0);
        acc1 = __builtin_amdgcn_mfma_f32_16x16x32_bf16(afr[s], bfr[1][s], acc1, 0, 0, 0);
      }

      // C/D layout (HW-verified): col = lane&15, row = (lane>>4)*4 + reg
#pragma unroll
      for (int r = 0; r < 4; ++r) {
        const int rl = lg * 4 + r;
        if (m0 + rl < cnt) {
          float* yp = y + (size_t)(tok0 + s_list[t][m0 + rl]) * kD + w * 32 + lr;
          yp[0]  = acc0[r] + bias0;
          yp[16] = acc1[r] + bias1;
        }
      }
    }
  }
}

extern "C" void kernel_launch(void* const* d_in, const int* in_sizes, int n_in,
                              void* d_out, int out_size, void* d_ws, size_t ws_size,
                              hipStream_t stream) {
  const float* x     = (const float*)d_in[0];
  const int*   types = (const int*)d_in[1];
  const float* W     = (const float*)d_in[2];
  const float* bias  = (const float*)d_in[3];
  float*       y     = (float*)d_out;
  short*       Wb    = (short*)d_ws;   // 8*128*128 bf16 = 256 KiB scratch

  const int n_tok = in_sizes[0] / kD;  // 131072

  wconv_kernel<<<(kT * kD * kD) / (256 * 8), 256, 0, stream>>>(W, Wb);
  typed_linear_kernel<<<n_tok / kBT, 256, 0, stream>>>(x, types, Wb, bias, y);
}